// Round 1
// baseline (2051.094 us; speedup 1.0000x reference)
//
#include <hip/hip_runtime.h>
#include <hip/hip_fp16.h>

#define B_ 256
#define T_ 512
#define I_ 30
#define H_ 128
#define G_ 512  // 4*H

__device__ __forceinline__ float sigmoid_f(float a) {
    return 1.f / (1.f + __expf(-a));
}
__device__ __forceinline__ float tanh_f(float a) {
    // robust for large |a|: a->+inf: exp=inf -> 1; a->-inf: exp=0 -> -1
    return 1.f - 2.f / (__expf(2.f * a) + 1.f);
}

// ---------------- layer 0: on-the-fly x-projection + recurrence ----------------
__global__ __launch_bounds__(512, 2)
void lstm0_kernel(const float* __restrict__ x,
                  const float* __restrict__ Wih, const float* __restrict__ Whh,
                  const float* __restrict__ bih, const float* __restrict__ bhh,
                  __half* __restrict__ h1out)
{
    const int b = blockIdx.x;
    const int g = threadIdx.x;  // gate index 0..511

    float w[H_];
    const float4* W4 = reinterpret_cast<const float4*>(Whh + (size_t)g * H_);
#pragma unroll
    for (int k = 0; k < H_ / 4; ++k) {
        float4 v = W4[k];
        w[4*k+0] = v.x; w[4*k+1] = v.y; w[4*k+2] = v.z; w[4*k+3] = v.w;
    }
    float wi[32];
#pragma unroll
    for (int i = 0; i < I_; ++i) wi[i] = Wih[g * I_ + i];
    wi[30] = 0.f; wi[31] = 0.f;
    float bias = bih[g] + bhh[g];

    __shared__ __align__(16) float h_s[H_];
    __shared__ __align__(16) float xs[32];
    __shared__ float gs[G_];
    float c = 0.f;
    if (g < H_) h_s[g] = 0.f;
    if (g < 32) xs[g] = (g < I_) ? x[((size_t)b * T_ + 0) * I_ + g] : 0.f;
    __syncthreads();

    for (int t = 0; t < T_; ++t) {
        // early-issue prefetch of next timestep's x (wave 7)
        float xv = 0.f;
        int pi = g - 480;
        if (pi >= 0 && pi < I_ && t + 1 < T_) xv = x[((size_t)b * T_ + t + 1) * I_ + pi];

        float acc = bias;
#pragma unroll
        for (int k4 = 0; k4 < 8; ++k4) {
            float4 x4 = *reinterpret_cast<const float4*>(&xs[4 * k4]);
            acc += wi[4*k4+0]*x4.x + wi[4*k4+1]*x4.y + wi[4*k4+2]*x4.z + wi[4*k4+3]*x4.w;
        }
#pragma unroll
        for (int k4 = 0; k4 < H_ / 4; ++k4) {
            float4 h4 = *reinterpret_cast<const float4*>(&h_s[4 * k4]);
            acc += w[4*k4+0]*h4.x + w[4*k4+1]*h4.y + w[4*k4+2]*h4.z + w[4*k4+3]*h4.w;
        }
        // activation computed by owner thread (wave-uniform branch: g>>7)
        float act = (((g >> 7) & 3) == 2) ? tanh_f(acc) : sigmoid_f(acc);
        gs[g] = act;
        __syncthreads();
        if (pi >= 0 && pi < I_ && t + 1 < T_) xs[pi] = xv;
        if (g < H_) {
            float ig = gs[g], fg = gs[g + H_], gg = gs[g + 2*H_], og = gs[g + 3*H_];
            c = fg * c + ig * gg;
            float h = og * tanh_f(c);
            h_s[g] = h;
            h1out[((size_t)b * T_ + t) * H_ + g] = __float2half(h);
        }
        __syncthreads();
    }
}

// ---------------- layer 1 input projection (register-stationary GEMM) ----------------
__global__ __launch_bounds__(512, 2)
void xp1_gemm_kernel(const __half* __restrict__ h1,
                     const float* __restrict__ Wih,
                     const float* __restrict__ bih, const float* __restrict__ bhh,
                     __half* __restrict__ xp, int t0, int tc)
{
    const int b   = blockIdx.y;
    const int sub = blockIdx.x;
    const int nsub = gridDim.x;
    const int g = threadIdx.x;
    const int steps = tc / nsub;
    const int ts = t0 + sub * steps;

    float w[H_];
    const float4* W4 = reinterpret_cast<const float4*>(Wih + (size_t)g * H_);
#pragma unroll
    for (int k = 0; k < H_ / 4; ++k) {
        float4 v = W4[k];
        w[4*k+0] = v.x; w[4*k+1] = v.y; w[4*k+2] = v.z; w[4*k+3] = v.w;
    }
    float bias = bih[g] + bhh[g];

    __shared__ __align__(16) float hsA[H_], hsB[H_];
    float rv = 0.f;
    if (g < H_) rv = __half2float(h1[((size_t)b * T_ + ts) * H_ + g]);
    if (g < H_) hsA[g] = rv;
    __syncthreads();

    for (int i = 0; i < steps; ++i) {
        int t = ts + i;
        float nxt = 0.f;
        if (g < H_ && i + 1 < steps) nxt = __half2float(h1[((size_t)b * T_ + t + 1) * H_ + g]);
        const float* hs = (i & 1) ? hsB : hsA;
        float acc = bias;
#pragma unroll
        for (int k4 = 0; k4 < H_ / 4; ++k4) {
            float4 h4 = *reinterpret_cast<const float4*>(&hs[4 * k4]);
            acc += w[4*k4+0]*h4.x + w[4*k4+1]*h4.y + w[4*k4+2]*h4.z + w[4*k4+3]*h4.w;
        }
        xp[((size_t)b * tc + (t - t0)) * G_ + g] = __float2half(acc);
        float* hsn = (i & 1) ? hsA : hsB;
        if (g < H_ && i + 1 < steps) hsn[g] = nxt;
        __syncthreads();
    }
}

// ---------------- layer 1 recurrence ----------------
__global__ __launch_bounds__(512, 2)
void lstm1_kernel(const __half* __restrict__ xp,
                  const float* __restrict__ Whh,
                  __half* __restrict__ h2out,
                  float* __restrict__ hstate, float* __restrict__ cstate,
                  int t0, int tc)
{
    const int b = blockIdx.x;
    const int g = threadIdx.x;

    float w[H_];
    const float4* W4 = reinterpret_cast<const float4*>(Whh + (size_t)g * H_);
#pragma unroll
    for (int k = 0; k < H_ / 4; ++k) {
        float4 v = W4[k];
        w[4*k+0] = v.x; w[4*k+1] = v.y; w[4*k+2] = v.z; w[4*k+3] = v.w;
    }

    __shared__ __align__(16) float h_s[H_];
    __shared__ float gs[G_];
    float c = 0.f;
    if (g < H_) {
        if (t0 == 0) h_s[g] = 0.f;
        else { h_s[g] = hstate[b * H_ + g]; c = cstate[b * H_ + g]; }
    }
    __syncthreads();

    float cur = __half2float(xp[((size_t)b * tc + 0) * G_ + g]);
    for (int i = 0; i < tc; ++i) {
        __half nv = __float2half(0.f);
        if (i + 1 < tc) nv = xp[((size_t)b * tc + i + 1) * G_ + g];  // early-issue prefetch
        float acc = cur;
#pragma unroll
        for (int k4 = 0; k4 < H_ / 4; ++k4) {
            float4 h4 = *reinterpret_cast<const float4*>(&h_s[4 * k4]);
            acc += w[4*k4+0]*h4.x + w[4*k4+1]*h4.y + w[4*k4+2]*h4.z + w[4*k4+3]*h4.w;
        }
        float act = (((g >> 7) & 3) == 2) ? tanh_f(acc) : sigmoid_f(acc);
        gs[g] = act;
        __syncthreads();
        if (g < H_) {
            float ig = gs[g], fg = gs[g + H_], gg = gs[g + 2*H_], og = gs[g + 3*H_];
            c = fg * c + ig * gg;
            float h = og * tanh_f(c);
            h_s[g] = h;
            h2out[((size_t)b * T_ + (t0 + i)) * H_ + g] = __float2half(h);
        }
        __syncthreads();
        cur = __half2float(nv);
    }
    if (g < H_) { hstate[b * H_ + g] = h_s[g]; cstate[b * H_ + g] = c; }
}

// ---------------- collapse the two linear layers: Wc = Wo@Wl, bc = Wo@bl + bo ----------------
__global__ void prep_kernel(const float* __restrict__ Wl, const float* __restrict__ bl,
                            const float* __restrict__ Wo, const float* __restrict__ bo,
                            float* __restrict__ Wc, float* __restrict__ bc)
{
    int tid = threadIdx.x;  // 256
    for (int idx = tid; idx < 64 * H_; idx += 256) {
        int j = idx / H_, k = idx % H_;
        float acc = 0.f;
        if (j < 63) {
            for (int m = 0; m < 84; ++m) acc += Wo[j * 84 + m] * Wl[m * H_ + k];
        }
        Wc[idx] = acc;  // row 63 zeroed (padding)
    }
    if (tid < 63) {
        float acc = bo[tid];
        for (int m = 0; m < 84; ++m) acc += Wo[tid * 84 + m] * bl[m];
        bc[tid] = acc;
    }
    if (tid == 63) bc[63] = 0.f;
}

// ---------------- head: out = h2 @ Wc.T + bc ----------------
__global__ __launch_bounds__(256)
void head_kernel(const __half* __restrict__ h2, const float* __restrict__ Wc,
                 const float* __restrict__ bc, float* __restrict__ out)
{
    const int tid = threadIdx.x;
    const int j = tid & 63;
    const int r = tid >> 6;  // 0..3
    const size_t rowbase = (size_t)blockIdx.x * 64;

    __shared__ __align__(16) float h2s[64 * H_];
    // stage 64 rows of h2 (half -> float)
    const uint4* src = reinterpret_cast<const uint4*>(h2 + rowbase * H_);
    for (int idx = tid; idx < 64 * H_ / 8; idx += 256) {
        uint4 u = src[idx];
        const __half2* hp = reinterpret_cast<const __half2*>(&u);
        float* d = &h2s[idx * 8];
#pragma unroll
        for (int q = 0; q < 4; ++q) {
            float2 f = __half22float2(hp[q]);
            d[2*q] = f.x; d[2*q+1] = f.y;
        }
    }
    float wc[H_];
    const float4* Wc4 = reinterpret_cast<const float4*>(Wc + (size_t)j * H_);
#pragma unroll
    for (int k = 0; k < H_ / 4; ++k) {
        float4 v = Wc4[k];
        wc[4*k+0] = v.x; wc[4*k+1] = v.y; wc[4*k+2] = v.z; wc[4*k+3] = v.w;
    }
    float bj = (j < 63) ? bc[j] : 0.f;
    __syncthreads();

    for (int rr = r; rr < 64; rr += 4) {
        float acc = bj;
#pragma unroll
        for (int k4 = 0; k4 < H_ / 4; ++k4) {
            float4 h4 = *reinterpret_cast<const float4*>(&h2s[rr * H_ + 4 * k4]);
            acc += wc[4*k4+0]*h4.x + wc[4*k4+1]*h4.y + wc[4*k4+2]*h4.z + wc[4*k4+3]*h4.w;
        }
        if (j < 63) out[(rowbase + rr) * 63 + j] = acc;
    }
}

extern "C" void kernel_launch(void* const* d_in, const int* in_sizes, int n_in,
                              void* d_out, int out_size, void* d_ws, size_t ws_size,
                              hipStream_t stream)
{
    const float* x    = (const float*)d_in[0];
    const float* Wih0 = (const float*)d_in[1];
    const float* Whh0 = (const float*)d_in[2];
    const float* bih0 = (const float*)d_in[3];
    const float* bhh0 = (const float*)d_in[4];
    const float* Wih1 = (const float*)d_in[5];
    const float* Whh1 = (const float*)d_in[6];
    const float* bih1 = (const float*)d_in[7];
    const float* bhh1 = (const float*)d_in[8];
    const float* Wl   = (const float*)d_in[9];
    const float* bl   = (const float*)d_in[10];
    const float* Wo   = (const float*)d_in[11];
    const float* bo   = (const float*)d_in[12];
    float* out = (float*)d_out;

    char* ws = (char*)d_ws;
    size_t off = 0;
    __half* h1 = (__half*)(ws + off); off += (size_t)B_ * T_ * H_ * sizeof(__half);
    __half* h2 = (__half*)(ws + off); off += (size_t)B_ * T_ * H_ * sizeof(__half);
    float* hstate = (float*)(ws + off); off += (size_t)B_ * H_ * sizeof(float);
    float* cstate = (float*)(ws + off); off += (size_t)B_ * H_ * sizeof(float);
    float* Wc = (float*)(ws + off); off += (size_t)64 * H_ * sizeof(float);
    float* bc = (float*)(ws + off); off += 64 * sizeof(float);
    __half* xp = (__half*)(ws + off);
    size_t rem = (ws_size > off) ? (ws_size - off) : 0;

    int TC = 512;
    if ((size_t)B_ * TC * G_ * sizeof(__half) > rem) TC = 64;
    if ((size_t)B_ * TC * G_ * sizeof(__half) > rem) TC = 16;

    hipLaunchKernelGGL(prep_kernel, dim3(1), dim3(256), 0, stream, Wl, bl, Wo, bo, Wc, bc);
    hipLaunchKernelGGL(lstm0_kernel, dim3(B_), dim3(512), 0, stream,
                       x, Wih0, Whh0, bih0, bhh0, h1);

    int nch = T_ / TC;
    for (int c0 = 0; c0 < nch; ++c0) {
        int t0 = c0 * TC;
        int nsub = (TC >= 64) ? (TC / 64) : 1;
        hipLaunchKernelGGL(xp1_gemm_kernel, dim3(nsub, B_), dim3(512), 0, stream,
                           h1, Wih1, bih1, bhh1, xp, t0, TC);
        hipLaunchKernelGGL(lstm1_kernel, dim3(B_), dim3(512), 0, stream,
                           xp, Whh1, h2, hstate, cstate, t0, TC);
    }
    hipLaunchKernelGGL(head_kernel, dim3((B_ * T_) / 64), dim3(256), 0, stream,
                       h2, Wc, bc, out);
}

// Round 2
// 1236.292 us; speedup vs baseline: 1.6591x; 1.6591x over previous
//
#include <hip/hip_runtime.h>
#include <hip/hip_fp16.h>

#define B_ 256
#define T_ 512
#define H_ 128
#define M_ (B_ * T_)  // 131072 rows

typedef _Float16 f16x2 __attribute__((ext_vector_type(2)));
typedef _Float16 f16x8 __attribute__((ext_vector_type(8)));
typedef float    f32x4 __attribute__((ext_vector_type(4)));

__device__ __forceinline__ float sigmoid_f(float a) { return 1.f / (1.f + __expf(-a)); }
__device__ __forceinline__ float tanh_f(float a) { return 1.f - 2.f / (__expf(2.f * a) + 1.f); }

// ---------- one-time conversions: fp16 weights, fused biases, collapsed head ----------
__global__ __launch_bounds__(256)
void convert_kernel(const float* __restrict__ x,
                    const float* __restrict__ Wih0, const float* __restrict__ bih0, const float* __restrict__ bhh0,
                    const float* __restrict__ Wih1, const float* __restrict__ bih1, const float* __restrict__ bhh1,
                    const float* __restrict__ Wl, const float* __restrict__ bl,
                    const float* __restrict__ Wo, const float* __restrict__ bo,
                    __half* __restrict__ x16, __half* __restrict__ W0h, __half* __restrict__ W1h,
                    __half* __restrict__ Wc16, float* __restrict__ b0, float* __restrict__ b1,
                    float* __restrict__ bc)
{
    const int tid = threadIdx.x, bid = blockIdx.x;
    if (bid == 0) {
        for (int i = tid; i < 512; i += 256) { b0[i] = bih0[i] + bhh0[i]; b1[i] = bih1[i] + bhh1[i]; }
        for (int i = tid; i < 512 * 32; i += 256) {
            int r = i >> 5, k = i & 31;
            W0h[i] = __float2half(k < 30 ? Wih0[r * 30 + k] : 0.f);
        }
        for (int i = tid; i < 512 * 128; i += 256) W1h[i] = __float2half(Wih1[i]);
        for (int i = tid; i < 64 * 128; i += 256) {
            int j = i >> 7, k = i & 127;
            float a = 0.f;
            if (j < 63) for (int m = 0; m < 84; ++m) a += Wo[j * 84 + m] * Wl[m * 128 + k];
            Wc16[i] = __float2half(a);
        }
        if (tid < 64) {
            float a = 0.f;
            if (tid < 63) { a = bo[tid]; for (int m = 0; m < 84; ++m) a += Wo[tid * 84 + m] * bl[m]; }
            bc[tid] = a;
        }
    } else {
        const int base = (bid - 1) * 256;  // row base
        const float* xs = x + (size_t)base * 30;
        for (int i = tid; i < 256 * 30; i += 256) {
            int r = i / 30, k = i - r * 30;
            x16[(size_t)(base + r) * 32 + k] = __float2half(xs[i]);
        }
        for (int i = tid; i < 512; i += 256) {
            int r = i >> 1, k = 30 + (i & 1);
            x16[(size_t)(base + r) * 32 + k] = __float2half(0.f);
        }
    }
}

// ---------- generic MFMA projection: out[M][NN] = in[M][KK] @ W16^T + bias ----------
// 256 threads = 4 waves; waves split NN; each block does 16*ROWT rows.
template<int KK, int NN, int ROWT, bool F32OUT>
__global__ __launch_bounds__(256, 4)
void proj_kernel(const __half* __restrict__ in, const __half* __restrict__ W16,
                 const float* __restrict__ bias, void* __restrict__ outp)
{
    constexpr int COLT = NN / 64;  // col-tiles per wave
    constexpr int KT = KK / 32;
    const int lane = threadIdx.x & 63;
    const int wn = threadIdx.x >> 6;
    const int rowbase = blockIdx.x * (16 * ROWT);
    const int colbase = wn * (COLT * 16);
    const int l15 = lane & 15, lk = (lane >> 4) * 8;

    float bcol[COLT];
#pragma unroll
    for (int ct = 0; ct < COLT; ++ct) bcol[ct] = bias[colbase + ct * 16 + l15];

    f32x4 acc[ROWT][COLT];
#pragma unroll
    for (int rt = 0; rt < ROWT; ++rt)
#pragma unroll
        for (int ct = 0; ct < COLT; ++ct) acc[rt][ct] = (f32x4){0.f, 0.f, 0.f, 0.f};

#pragma unroll
    for (int kt = 0; kt < KT; ++kt) {
        f16x8 a[ROWT];
#pragma unroll
        for (int rt = 0; rt < ROWT; ++rt)
            a[rt] = *reinterpret_cast<const f16x8*>(in + (size_t)(rowbase + rt * 16 + l15) * KK + kt * 32 + lk);
#pragma unroll
        for (int ct = 0; ct < COLT; ++ct) {
            f16x8 bv = *reinterpret_cast<const f16x8*>(W16 + (size_t)(colbase + ct * 16 + l15) * KK + kt * 32 + lk);
#pragma unroll
            for (int rt = 0; rt < ROWT; ++rt)
                acc[rt][ct] = __builtin_amdgcn_mfma_f32_16x16x32_f16(a[rt], bv, acc[rt][ct], 0, 0, 0);
        }
    }
#pragma unroll
    for (int ct = 0; ct < COLT; ++ct) {
        const int col = colbase + ct * 16 + l15;
#pragma unroll
        for (int rt = 0; rt < ROWT; ++rt) {
#pragma unroll
            for (int r = 0; r < 4; ++r) {
                const int row = rowbase + rt * 16 + (lane >> 4) * 4 + r;
                float v = acc[rt][ct][r] + bcol[ct];
                if constexpr (F32OUT) {
                    if (col < 63) ((float*)outp)[(size_t)row * 63 + col] = v;
                } else {
                    ((__half*)outp)[(size_t)row * NN + col] = __float2half(v);
                }
            }
        }
    }
}

// ---------- recurrence: thread (j,kq) owns gates {i,f,g,o} of unit j over k-quarter kq ----------
#define FD(q, idx, av) p##q = __builtin_amdgcn_fdot2(w[q][idx], av, p##q, false)

__global__ __launch_bounds__(512, 4)
void lstm_rec_kernel(const __half* __restrict__ xp, const float* __restrict__ Whh,
                     __half* __restrict__ hout)
{
    const int b = blockIdx.x;
    const int tid = threadIdx.x;
    const int j = tid >> 2, kq = tid & 3;

    // weights: 4 gate rows x 32 halfs (as 16 f16x2 each) -> 64 VGPRs
    f16x2 w[4][16];
#pragma unroll
    for (int q = 0; q < 4; ++q) {
        const float4* wr = reinterpret_cast<const float4*>(Whh + (size_t)((q << 7) + j) * 128 + (kq << 5));
#pragma unroll
        for (int p = 0; p < 8; ++p) {
            float4 v = wr[p];
            w[q][p * 2]     = (f16x2){(_Float16)v.x, (_Float16)v.y};
            w[q][p * 2 + 1] = (f16x2){(_Float16)v.z, (_Float16)v.w};
        }
    }

    __shared__ __align__(16) __half h_s[H_];
    if (tid < 128) h_s[tid] = __float2half(0.f);
    __syncthreads();

    float c = 0.f;
    const size_t xbase = (size_t)b * T_ * 512 + kq * 128 + j;
    float xv = __half2float(xp[xbase]);  // t = 0 (bias already folded in)
    for (int t = 0; t < T_; ++t) {
        float xn = 0.f;
        if (t + 1 < T_) xn = __half2float(xp[xbase + (size_t)(t + 1) * 512]);  // prefetch

        const uint4* hp = reinterpret_cast<const uint4*>(h_s) + kq * 4;  // 64 B slice
        float p0 = 0.f, p1 = 0.f, p2 = 0.f, p3 = 0.f;
#pragma unroll
        for (int cc = 0; cc < 4; ++cc) {
            uint4 hv = hp[cc];
            f16x2 a0 = __builtin_bit_cast(f16x2, hv.x);
            f16x2 a1 = __builtin_bit_cast(f16x2, hv.y);
            f16x2 a2 = __builtin_bit_cast(f16x2, hv.z);
            f16x2 a3 = __builtin_bit_cast(f16x2, hv.w);
            FD(0, cc * 4 + 0, a0); FD(0, cc * 4 + 1, a1); FD(0, cc * 4 + 2, a2); FD(0, cc * 4 + 3, a3);
            FD(1, cc * 4 + 0, a0); FD(1, cc * 4 + 1, a1); FD(1, cc * 4 + 2, a2); FD(1, cc * 4 + 3, a3);
            FD(2, cc * 4 + 0, a0); FD(2, cc * 4 + 1, a1); FD(2, cc * 4 + 2, a2); FD(2, cc * 4 + 3, a3);
            FD(3, cc * 4 + 0, a0); FD(3, cc * 4 + 1, a1); FD(3, cc * 4 + 2, a2); FD(3, cc * 4 + 3, a3);
        }
        // add xp (with bias) exactly once per gate: lane kq contributes gate kq
        p0 += (kq == 0) ? xv : 0.f;
        p1 += (kq == 1) ? xv : 0.f;
        p2 += (kq == 2) ? xv : 0.f;
        p3 += (kq == 3) ? xv : 0.f;
        // quad butterfly: all 4 lanes get full 128-length sums of all 4 gates
        p0 += __shfl_xor(p0, 1); p1 += __shfl_xor(p1, 1); p2 += __shfl_xor(p2, 1); p3 += __shfl_xor(p3, 1);
        p0 += __shfl_xor(p0, 2); p1 += __shfl_xor(p1, 2); p2 += __shfl_xor(p2, 2); p3 += __shfl_xor(p3, 2);
        __syncthreads();  // all h_s reads complete before overwrite
        float iv = sigmoid_f(p0), fv = sigmoid_f(p1);
        float gv = tanh_f(p2),   ov = sigmoid_f(p3);
        c = fv * c + iv * gv;
        float h = ov * tanh_f(c);
        if (kq == 0) {
            __half hh = __float2half(h);
            h_s[j] = hh;
            hout[(size_t)(b * T_ + t) * H_ + j] = hh;
        }
        __syncthreads();
        xv = xn;
    }
}

extern "C" void kernel_launch(void* const* d_in, const int* in_sizes, int n_in,
                              void* d_out, int out_size, void* d_ws, size_t ws_size,
                              hipStream_t stream)
{
    const float* x    = (const float*)d_in[0];
    const float* Wih0 = (const float*)d_in[1];
    const float* Whh0 = (const float*)d_in[2];
    const float* bih0 = (const float*)d_in[3];
    const float* bhh0 = (const float*)d_in[4];
    const float* Wih1 = (const float*)d_in[5];
    const float* Whh1 = (const float*)d_in[6];
    const float* bih1 = (const float*)d_in[7];
    const float* bhh1 = (const float*)d_in[8];
    const float* Wl   = (const float*)d_in[9];
    const float* bl   = (const float*)d_in[10];
    const float* Wo   = (const float*)d_in[11];
    const float* bo   = (const float*)d_in[12];
    float* out = (float*)d_out;

    char* ws = (char*)d_ws;
    size_t off = 0;
    auto carve = [&](size_t bytes) { void* p = ws + off; off += (bytes + 255) & ~(size_t)255; return p; };
    __half* xp  = (__half*)carve((size_t)M_ * 512 * 2);  // 134 MB, shared by both layers
    __half* h1  = (__half*)carve((size_t)M_ * 128 * 2);  // 33.5 MB
    __half* h2  = (__half*)carve((size_t)M_ * 128 * 2);  // 33.5 MB
    __half* x16 = h2;                                    // alias: x16 (8.4 MB) dead before h2 written
    __half* W0h  = (__half*)carve(512 * 32 * 2);
    __half* W1h  = (__half*)carve(512 * 128 * 2);
    __half* Wc16 = (__half*)carve(64 * 128 * 2);
    float*  b0   = (float*)carve(512 * 4);
    float*  b1   = (float*)carve(512 * 4);
    float*  bc   = (float*)carve(64 * 4);

    hipLaunchKernelGGL(convert_kernel, dim3(1 + M_ / 256), dim3(256), 0, stream,
                       x, Wih0, bih0, bhh0, Wih1, bih1, bhh1, Wl, bl, Wo, bo,
                       x16, W0h, W1h, Wc16, b0, b1, bc);

    // layer 0: xp0 = x16 @ W0h^T + b0, then recurrence
    hipLaunchKernelGGL((proj_kernel<32, 512, 2, false>), dim3(M_ / 32), dim3(256), 0, stream,
                       x16, W0h, b0, (void*)xp);
    hipLaunchKernelGGL(lstm_rec_kernel, dim3(B_), dim3(512), 0, stream, xp, Whh0, h1);

    // layer 1: xp1 = h1 @ W1h^T + b1, then recurrence
    hipLaunchKernelGGL((proj_kernel<128, 512, 2, false>), dim3(M_ / 32), dim3(256), 0, stream,
                       h1, W1h, b1, (void*)xp);
    hipLaunchKernelGGL(lstm_rec_kernel, dim3(B_), dim3(512), 0, stream, xp, Whh1, h2);

    // head: out = h2 @ Wc^T + bc (63 cols, f32)
    hipLaunchKernelGGL((proj_kernel<128, 64, 4, true>), dim3(M_ / 64), dim3(256), 0, stream,
                       h2, Wc16, bc, (void*)out);
}